// Round 3
// baseline (325.788 us; speedup 1.0000x reference)
//
#include <hip/hip_runtime.h>

typedef __attribute__((ext_vector_type(8))) short short8;
typedef __attribute__((ext_vector_type(4))) float f32x4;

#define DEVI __device__ __forceinline__

DEVI float bf2f(unsigned short u) {
    unsigned v = ((unsigned)u) << 16;
    return __builtin_bit_cast(float, v);
}
DEVI unsigned short f2bf(float f) {
    unsigned u = __builtin_bit_cast(unsigned, f);
    u += 0x7fffu + ((u >> 16) & 1u);   // RNE
    return (unsigned short)(u >> 16);
}

// ---------------------------------------------------------------- transpose + cvt
// w[768][2304] f32 -> wt[2304][768] bf16
__global__ void ktrans(const float* __restrict__ w,
                       unsigned short* __restrict__ wt) {
    __shared__ float t[32][33];
    const int tx = threadIdx.x, ty = threadIdx.y;   // 32 x 8
    const int n0 = blockIdx.x * 32, k0 = blockIdx.y * 32;
#pragma unroll
    for (int i = 0; i < 4; i++)
        t[ty + i * 8][tx] = w[(k0 + ty + i * 8) * 2304 + n0 + tx];
    __syncthreads();
#pragma unroll
    for (int i = 0; i < 4; i++)
        wt[(n0 + ty + i * 8) * 768 + k0 + tx] = f2bf(t[tx][ty + i * 8]);
}

// ---------------------------------------------------------------- QKV GEMM
// A = x [8192][768] f32 (converted to bf16 during staging),
// Bt = wt [2304][768] bf16; C = A*Bt^T + bias (f32)
// scatter: which 0 -> Q[bh][s][d], 1 -> K[bh][s][d], 2 -> Vt[bh][d][s]  (bf16)
__global__ __launch_bounds__(256) void kgemm(
        const float* __restrict__ A,
        const unsigned short* __restrict__ Bt,
        const float* __restrict__ bias,
        unsigned short* __restrict__ q,
        unsigned short* __restrict__ k_,
        unsigned short* __restrict__ vt) {
    __shared__ __align__(16) unsigned short As[128 * 32];
    __shared__ __align__(16) unsigned short Bs[128 * 32];
    const int tid = threadIdx.x;
    const int w = tid >> 6, lane = tid & 63;
    const int wm = w >> 1, wn = w & 1;
    const int m0 = blockIdx.y * 128, n0 = blockIdx.x * 128;

    f32x4 acc[4][4] = {};

    const int frow = lane & 15;          // fragment row/col within tile
    const int fkof = (lane >> 4) * 8;    // fragment k offset

    for (int kk = 0; kk < 768; kk += 32) {
        __syncthreads();
        // staging: 4096 elems per array, 256 thr x 2 x 8 elems
#pragma unroll
        for (int j = 0; j < 2; j++) {
            const int e = (tid + j * 256) * 8;     // flat elem idx
            const int row = e >> 5, col = e & 31;  // 32 k per row
            const float4 a0 = *(const float4*)&A[(m0 + row) * 768 + kk + col];
            const float4 a1 = *(const float4*)&A[(m0 + row) * 768 + kk + col + 4];
            short8 av;
            av[0] = (short)f2bf(a0.x); av[1] = (short)f2bf(a0.y);
            av[2] = (short)f2bf(a0.z); av[3] = (short)f2bf(a0.w);
            av[4] = (short)f2bf(a1.x); av[5] = (short)f2bf(a1.y);
            av[6] = (short)f2bf(a1.z); av[7] = (short)f2bf(a1.w);
            *(short8*)&As[e] = av;
            *(short8*)&Bs[e] = *(const short8*)&Bt[(n0 + row) * 768 + kk + col];
        }
        __syncthreads();
        short8 af[4], bf[4];
#pragma unroll
        for (int mi = 0; mi < 4; mi++)
            af[mi] = *(const short8*)&As[(wm * 64 + mi * 16 + frow) * 32 + fkof];
#pragma unroll
        for (int ni = 0; ni < 4; ni++)
            bf[ni] = *(const short8*)&Bs[(wn * 64 + ni * 16 + frow) * 32 + fkof];
#pragma unroll
        for (int mi = 0; mi < 4; mi++)
#pragma unroll
            for (int ni = 0; ni < 4; ni++)
                acc[mi][ni] = __builtin_amdgcn_mfma_f32_16x16x32_bf16(
                    af[mi], bf[ni], acc[mi][ni], 0, 0, 0);
    }

    const int col0 = n0 + wn * 64;
    const int row0 = m0 + wm * 64;
#pragma unroll
    for (int mi = 0; mi < 4; mi++) {
#pragma unroll
        for (int ni = 0; ni < 4; ni++) {
            const int n_ = col0 + ni * 16 + (lane & 15);
            const float bv = bias[n_];
            const int which = n_ / 768;
            const int r7 = n_ % 768;
            const int h = r7 >> 6, d = r7 & 63;
#pragma unroll
            for (int r = 0; r < 4; r++) {
                const int m_ = row0 + mi * 16 + (lane >> 4) * 4 + r;
                const int bb = m_ >> 10, s = m_ & 1023;
                const int bh = bb * 12 + h;
                const unsigned short o = f2bf(acc[mi][ni][r] + bv);
                if (which == 0)      q[(bh * 1024 + s) * 64 + d] = o;
                else if (which == 1) k_[(bh * 1024 + s) * 64 + d] = o;
                else                 vt[(bh * 64 + d) * 1024 + s] = o;
            }
        }
    }
}

// ---------------------------------------------------------------- attention
#define SCL 0.18033688011112042f   // log2(e) / sqrt(64)

__global__ __launch_bounds__(256) void kattn(
        const unsigned short* __restrict__ q,
        const unsigned short* __restrict__ k_,
        const unsigned short* __restrict__ vt,
        float* __restrict__ out) {
    __shared__ __align__(16) unsigned short Ks[64 * 64];
    __shared__ __align__(16) unsigned short Vs[64 * 64];
    __shared__ __align__(16) unsigned short Ps[4][32 * 72];
    const int tid = threadIdx.x;
    const int w = tid >> 6, lane = tid & 63;
    const int bh = blockIdx.x;          // 96
    const int qt = blockIdx.y;          // 8
    const int bb = bh / 12, h = bh % 12;
    const unsigned short* qb = q + bh * 1024 * 64;
    const unsigned short* kb = k_ + bh * 1024 * 64;
    const unsigned short* vb = vt + bh * 64 * 1024;

    const int frow = lane & 15;
    const int grp = lane >> 4;
    const int m0 = qt * 128 + w * 32;   // wave's first Q row

    short8 qf[2][2];
#pragma unroll
    for (int mi = 0; mi < 2; mi++)
#pragma unroll
        for (int ks = 0; ks < 2; ks++)
            qf[mi][ks] = *(const short8*)&qb[(m0 + mi * 16 + frow) * 64 + ks * 32 + grp * 8];

    f32x4 oacc[2][4] = {};
    float rmax[2][4], rsum[2][4];
#pragma unroll
    for (int mi = 0; mi < 2; mi++)
#pragma unroll
        for (int r = 0; r < 4; r++) { rmax[mi][r] = -INFINITY; rsum[mi][r] = 0.f; }

    for (int t0 = 0; t0 < 1024; t0 += 64) {
        __syncthreads();
        // staging: 4096 elems each, 64 cols per row
#pragma unroll
        for (int j = 0; j < 2; j++) {
            const int e = (tid + j * 256) * 8;
            const int row = e >> 6, col = e & 63;
            *(short8*)&Ks[e] = *(const short8*)&kb[(t0 + row) * 64 + col];
            *(short8*)&Vs[e] = *(const short8*)&vb[row * 1024 + t0 + col];
        }
        __syncthreads();

        f32x4 sacc[2][4] = {};
#pragma unroll
        for (int ks = 0; ks < 2; ks++) {
            short8 bk[4];
#pragma unroll
            for (int ni = 0; ni < 4; ni++)
                bk[ni] = *(const short8*)&Ks[(ni * 16 + frow) * 64 + ks * 32 + grp * 8];
#pragma unroll
            for (int mi = 0; mi < 2; mi++)
#pragma unroll
                for (int ni = 0; ni < 4; ni++)
                    sacc[mi][ni] = __builtin_amdgcn_mfma_f32_16x16x32_bf16(
                        qf[mi][ks], bk[ni], sacc[mi][ni], 0, 0, 0);
        }

        // online softmax (rows: mi*16 + grp*4 + r, cols spread over lane&15)
#pragma unroll
        for (int mi = 0; mi < 2; mi++) {
#pragma unroll
            for (int r = 0; r < 4; r++) {
                float mt = fmaxf(fmaxf(sacc[mi][0][r], sacc[mi][1][r]),
                                 fmaxf(sacc[mi][2][r], sacc[mi][3][r]));
                mt = fmaxf(mt, __shfl_xor(mt, 1, 64));
                mt = fmaxf(mt, __shfl_xor(mt, 2, 64));
                mt = fmaxf(mt, __shfl_xor(mt, 4, 64));
                mt = fmaxf(mt, __shfl_xor(mt, 8, 64));
                const float mnew = fmaxf(rmax[mi][r], mt);
                const float alpha = exp2f((rmax[mi][r] - mnew) * SCL);
                rmax[mi][r] = mnew;
                float ps = 0.f;
#pragma unroll
                for (int ni = 0; ni < 4; ni++) {
                    const float p = exp2f((sacc[mi][ni][r] - mnew) * SCL);
                    sacc[mi][ni][r] = p;
                    ps += p;
                }
                ps += __shfl_xor(ps, 1, 64);
                ps += __shfl_xor(ps, 2, 64);
                ps += __shfl_xor(ps, 4, 64);
                ps += __shfl_xor(ps, 8, 64);
                rsum[mi][r] = rsum[mi][r] * alpha + ps;
#pragma unroll
                for (int di = 0; di < 4; di++) oacc[mi][di][r] *= alpha;
            }
        }

        // P -> per-wave LDS (C-layout -> A-layout relayout), stride 72 bf16
#pragma unroll
        for (int mi = 0; mi < 2; mi++)
#pragma unroll
            for (int ni = 0; ni < 4; ni++)
#pragma unroll
                for (int r = 0; r < 4; r++)
                    Ps[w][(mi * 16 + grp * 4 + r) * 72 + ni * 16 + frow] =
                        f2bf(sacc[mi][ni][r]);

        // P @ V
#pragma unroll
        for (int ks = 0; ks < 2; ks++) {
            short8 ap[2], bv[4];
#pragma unroll
            for (int mi = 0; mi < 2; mi++)
                ap[mi] = *(const short8*)&Ps[w][(mi * 16 + frow) * 72 + ks * 32 + grp * 8];
#pragma unroll
            for (int di = 0; di < 4; di++)
                bv[di] = *(const short8*)&Vs[(di * 16 + frow) * 64 + ks * 32 + grp * 8];
#pragma unroll
            for (int mi = 0; mi < 2; mi++)
#pragma unroll
                for (int di = 0; di < 4; di++)
                    oacc[mi][di] = __builtin_amdgcn_mfma_f32_16x16x32_bf16(
                        ap[mi], bv[di], oacc[mi][di], 0, 0, 0);
        }
    }

    // epilogue: O / l  -> out[b][s][h*64+d]  (f32)
#pragma unroll
    for (int mi = 0; mi < 2; mi++) {
#pragma unroll
        for (int r = 0; r < 4; r++) {
            const float inv = 1.0f / rsum[mi][r];
            const int s = m0 + mi * 16 + grp * 4 + r;
#pragma unroll
            for (int di = 0; di < 4; di++) {
                const int d = di * 16 + frow;
                out[(bb * 1024 + s) * 768 + h * 64 + d] = oacc[mi][di][r] * inv;
            }
        }
    }
}

// ---------------------------------------------------------------- residual + LN (f32)
__global__ __launch_bounds__(256) void kln(
        const float* __restrict__ x,
        const float* __restrict__ gamma,
        const float* __restrict__ beta,
        float* __restrict__ out) {
    __shared__ float red[8];
    const int row = blockIdx.x;
    const int tid = threadIdx.x;
    const float* xr = x + row * 768;
    float* orow = out + row * 768;
    float y[3], sum = 0.f, sumsq = 0.f;
#pragma unroll
    for (int i = 0; i < 3; i++) {
        const int e = tid + i * 256;
        const float v = xr[e] + orow[e];
        y[i] = v; sum += v; sumsq += v * v;
    }
#pragma unroll
    for (int o = 1; o < 64; o <<= 1) {
        sum += __shfl_xor(sum, o, 64);
        sumsq += __shfl_xor(sumsq, o, 64);
    }
    const int w = tid >> 6, lane = tid & 63;
    if (lane == 0) { red[w] = sum; red[4 + w] = sumsq; }
    __syncthreads();
    sum = red[0] + red[1] + red[2] + red[3];
    sumsq = red[4] + red[5] + red[6] + red[7];
    const float mean = sum * (1.0f / 768.0f);
    const float var = sumsq * (1.0f / 768.0f) - mean * mean;
    const float rs = rsqrtf(var + 1e-5f);
#pragma unroll
    for (int i = 0; i < 3; i++) {
        const int e = tid + i * 256;
        orow[e] = (y[i] - mean) * rs * gamma[e] + beta[e];
    }
}

// ---------------------------------------------------------------- launch
extern "C" void kernel_launch(void* const* d_in, const int* in_sizes, int n_in,
                              void* d_out, int out_size, void* d_ws, size_t ws_size,
                              hipStream_t stream) {
    (void)in_sizes; (void)n_in; (void)out_size; (void)ws_size;
    const float* x     = (const float*)d_in[0];
    const float* wqkv  = (const float*)d_in[1];
    const float* bqkv  = (const float*)d_in[2];
    const float* gamma = (const float*)d_in[3];
    const float* beta  = (const float*)d_in[4];
    float* out = (float*)d_out;
    unsigned short* ws = (unsigned short*)d_ws;

    unsigned short* wt = ws;                       // 2304*768  bf16
    unsigned short* q  = wt + 2304 * 768;          // 96*1024*64 bf16
    unsigned short* k  = q + 96 * 1024 * 64;       // 96*1024*64 bf16
    unsigned short* vt = k + 96 * 1024 * 64;       // 96*64*1024 bf16

    ktrans<<<dim3(72, 24), dim3(32, 8), 0, stream>>>(wqkv, wt);
    kgemm<<<dim3(18, 64), 256, 0, stream>>>(x, wt, bqkv, q, k, vt);
    kattn<<<dim3(96, 8), 256, 0, stream>>>(q, k, vt, out);
    kln<<<8192, 256, 0, stream>>>(x, gamma, beta, out);
}

// Round 4
// 245.809 us; speedup vs baseline: 1.3254x; 1.3254x over previous
//
#include <hip/hip_runtime.h>

typedef __attribute__((ext_vector_type(8))) short short8;
typedef __attribute__((ext_vector_type(4))) float f32x4;

#define DEVI __device__ __forceinline__

DEVI unsigned fbits(float f) { return __builtin_bit_cast(unsigned, f); }
DEVI unsigned short f2bf(float f) {
    unsigned u = __builtin_bit_cast(unsigned, f);
    u += 0x7fffu + ((u >> 16) & 1u);   // RNE
    return (unsigned short)(u >> 16);
}
// pack hi16(a), hi16(b) -> u32 [a_hi | b_hi<<16]  (bf16 truncation)
DEVI unsigned pktrunc(float a, float b) {
    return __builtin_amdgcn_perm(fbits(b), fbits(a), 0x07060302u);
}

// ---------------------------------------------------------------- transpose + cvt
// w[768][2304] f32 -> wt[2304][768] bf16
__global__ void ktrans(const float* __restrict__ w,
                       unsigned short* __restrict__ wt) {
    __shared__ float t[32][33];
    const int tx = threadIdx.x, ty = threadIdx.y;   // 32 x 8
    const int n0 = blockIdx.x * 32, k0 = blockIdx.y * 32;
#pragma unroll
    for (int i = 0; i < 4; i++)
        t[ty + i * 8][tx] = w[(k0 + ty + i * 8) * 2304 + n0 + tx];
    __syncthreads();
#pragma unroll
    for (int i = 0; i < 4; i++)
        wt[(n0 + ty + i * 8) * 768 + k0 + tx] = f2bf(t[tx][ty + i * 8]);
}

// ---------------------------------------------------------------- QKV GEMM
// A = x [8192][768] f32 (bf16-truncated during staging), Bt = wt [2304][768] bf16
// C = A*Bt^T + bias; scatter 0->Q[bh][s][d], 1->K[bh][s][d], 2->Vt[bh][d][s]
#define AST 40   // padded LDS row stride (elems): 80 B = 20 banks -> 2-way max
__global__ __launch_bounds__(256) void kgemm(
        const float* __restrict__ A,
        const unsigned short* __restrict__ Bt,
        const float* __restrict__ bias,
        unsigned short* __restrict__ q,
        unsigned short* __restrict__ k_,
        unsigned short* __restrict__ vt) {
    __shared__ __align__(16) unsigned short As[128 * AST];
    __shared__ __align__(16) unsigned short Bs[128 * AST];
    const int tid = threadIdx.x;
    const int w = tid >> 6, lane = tid & 63;
    const int wm = w >> 1, wn = w & 1;
    const int m0 = blockIdx.y * 128, n0 = blockIdx.x * 128;

    f32x4 acc[4][4] = {};

    const int frow = lane & 15;
    const int fkof = (lane >> 4) * 8;

    for (int kk = 0; kk < 768; kk += 32) {
        __syncthreads();
#pragma unroll
        for (int j = 0; j < 2; j++) {
            const int e = (tid + j * 256) * 8;
            const int row = e >> 5, col = e & 31;
            const float4 a0 = *(const float4*)&A[(m0 + row) * 768 + kk + col];
            const float4 a1 = *(const float4*)&A[(m0 + row) * 768 + kk + col + 4];
            uint4 pk;
            pk.x = pktrunc(a0.x, a0.y);
            pk.y = pktrunc(a0.z, a0.w);
            pk.z = pktrunc(a1.x, a1.y);
            pk.w = pktrunc(a1.z, a1.w);
            *(uint4*)&As[row * AST + col] = pk;
            *(short8*)&Bs[row * AST + col] = *(const short8*)&Bt[(n0 + row) * 768 + kk + col];
        }
        __syncthreads();
        short8 af[4], bf[4];
#pragma unroll
        for (int mi = 0; mi < 4; mi++)
            af[mi] = *(const short8*)&As[(wm * 64 + mi * 16 + frow) * AST + fkof];
#pragma unroll
        for (int ni = 0; ni < 4; ni++)
            bf[ni] = *(const short8*)&Bs[(wn * 64 + ni * 16 + frow) * AST + fkof];
#pragma unroll
        for (int mi = 0; mi < 4; mi++)
#pragma unroll
            for (int ni = 0; ni < 4; ni++)
                acc[mi][ni] = __builtin_amdgcn_mfma_f32_16x16x32_bf16(
                    af[mi], bf[ni], acc[mi][ni], 0, 0, 0);
    }

    const int col0 = n0 + wn * 64;
    const int row0 = m0 + wm * 64;
#pragma unroll
    for (int mi = 0; mi < 4; mi++) {
#pragma unroll
        for (int ni = 0; ni < 4; ni++) {
            const int n_ = col0 + ni * 16 + (lane & 15);
            const float bv = bias[n_];
            const int which = n_ / 768;
            const int r7 = n_ % 768;
            const int h = r7 >> 6, d = r7 & 63;
#pragma unroll
            for (int r = 0; r < 4; r++) {
                const int m_ = row0 + mi * 16 + (lane >> 4) * 4 + r;
                const int bb = m_ >> 10, s = m_ & 1023;
                const int bh = bb * 12 + h;
                const unsigned short o = f2bf(acc[mi][ni][r] + bv);
                if (which == 0)      q[(bh * 1024 + s) * 64 + d] = o;
                else if (which == 1) k_[(bh * 1024 + s) * 64 + d] = o;
                else                 vt[(bh * 64 + d) * 1024 + s] = o;
            }
        }
    }
}

// ---------------------------------------------------------------- attention
// Transposed-S structure: S^T = K*Q^T, softmax over S^T rows (= keys),
// O^T = V^T * P^T.  Lane's frow == q-row throughout -> 2-step shfl
// reductions, b64 P stores, b128 P reads, float4 O stores.
#define SCL 0.18033688011112042f   // log2(e) / sqrt(64)
#define KST 72   // padded LDS row stride: 144 B = 4 banks/row offset -> 2-way

__global__ __launch_bounds__(256) void kattn(
        const unsigned short* __restrict__ q,
        const unsigned short* __restrict__ k_,
        const unsigned short* __restrict__ vt,
        float* __restrict__ out) {
    __shared__ __align__(16) unsigned short Ks[64 * KST];
    __shared__ __align__(16) unsigned short Vs[64 * KST];
    __shared__ __align__(16) unsigned short Ps[4][32 * KST];
    const int tid = threadIdx.x;
    const int w = tid >> 6, lane = tid & 63;
    const int bh = blockIdx.x;          // 96
    const int qt = blockIdx.y;          // 8
    const int bb = bh / 12, h = bh % 12;
    const unsigned short* qb = q + bh * 1024 * 64;
    const unsigned short* kb = k_ + bh * 1024 * 64;
    const unsigned short* vb = vt + bh * 64 * 1024;

    const int frow = lane & 15;         // = q-row (within 16-tile) everywhere
    const int grp = lane >> 4;
    const int m0 = qt * 128 + w * 32;   // wave's first Q row

    // Q fragments, Bt-form: Q[m0+mi*16+frow][ks*32+grp*8 ..]
    short8 qf[2][2];
#pragma unroll
    for (int mi = 0; mi < 2; mi++)
#pragma unroll
        for (int ks = 0; ks < 2; ks++)
            qf[mi][ks] = *(const short8*)&qb[(m0 + mi * 16 + frow) * 64 + ks * 32 + grp * 8];

    f32x4 oacc[2][4] = {};              // [mi][di]: O^T tile rows=d, cols=q
    float rmax[2] = {-INFINITY, -INFINITY}, rsum[2] = {0.f, 0.f};

    for (int t0 = 0; t0 < 1024; t0 += 64) {
        __syncthreads();
#pragma unroll
        for (int j = 0; j < 2; j++) {
            const int e = (tid + j * 256) * 8;
            const int row = e >> 6, col = e & 63;
            *(short8*)&Ks[row * KST + col] = *(const short8*)&kb[(t0 + row) * 64 + col];
            *(short8*)&Vs[row * KST + col] = *(const short8*)&vb[row * 1024 + t0 + col];
        }
        __syncthreads();

        // S^T = K * Q^T   (A = K-tile, B = Q)
        f32x4 sacc[4][2] = {};          // [ni(key-tile)][mi(q-tile)]
#pragma unroll
        for (int ks = 0; ks < 2; ks++) {
            short8 kf[4];
#pragma unroll
            for (int ni = 0; ni < 4; ni++)
                kf[ni] = *(const short8*)&Ks[(ni * 16 + frow) * KST + ks * 32 + grp * 8];
#pragma unroll
            for (int ni = 0; ni < 4; ni++)
#pragma unroll
                for (int mi = 0; mi < 2; mi++)
                    sacc[ni][mi] = __builtin_amdgcn_mfma_f32_16x16x32_bf16(
                        kf[ni], qf[mi][ks], sacc[ni][mi], 0, 0, 0);
        }

        // online softmax: lane holds 16 keys (ni,r) for q-row mi*16+frow
#pragma unroll
        for (int mi = 0; mi < 2; mi++) {
            float mt = -INFINITY;
#pragma unroll
            for (int ni = 0; ni < 4; ni++)
#pragma unroll
                for (int r = 0; r < 4; r++) mt = fmaxf(mt, sacc[ni][mi][r]);
            mt = fmaxf(mt, __shfl_xor(mt, 16, 64));
            mt = fmaxf(mt, __shfl_xor(mt, 32, 64));
            const float mnew = fmaxf(rmax[mi], mt);
            const float alpha = exp2f((rmax[mi] - mnew) * SCL);
            rmax[mi] = mnew;
            const float mb = mnew * SCL;
            float ps = 0.f;
#pragma unroll
            for (int ni = 0; ni < 4; ni++)
#pragma unroll
                for (int r = 0; r < 4; r++) {
                    const float p = exp2f(sacc[ni][mi][r] * SCL - mb);
                    sacc[ni][mi][r] = p;
                    ps += p;
                }
            ps += __shfl_xor(ps, 16, 64);
            ps += __shfl_xor(ps, 32, 64);
            rsum[mi] = rsum[mi] * alpha + ps;
#pragma unroll
            for (int di = 0; di < 4; di++) oacc[mi][di] *= alpha;
            // store P^T row (4 consecutive keys) as one b64 per (mi,ni)
#pragma unroll
            for (int ni = 0; ni < 4; ni++) {
                uint2 pk;
                pk.x = pktrunc(sacc[ni][mi][0], sacc[ni][mi][1]);
                pk.y = pktrunc(sacc[ni][mi][2], sacc[ni][mi][3]);
                *(uint2*)&Ps[w][(mi * 16 + frow) * KST + ni * 16 + grp * 4] = pk;
            }
        }

        // O^T += V^T * P^T   (A = V^T-tile from Vs[d][key], B = P)
#pragma unroll
        for (int ks = 0; ks < 2; ks++) {
            short8 vf[4], pf[2];
#pragma unroll
            for (int di = 0; di < 4; di++)
                vf[di] = *(const short8*)&Vs[(di * 16 + frow) * KST + ks * 32 + grp * 8];
#pragma unroll
            for (int mi = 0; mi < 2; mi++)
                pf[mi] = *(const short8*)&Ps[w][(mi * 16 + frow) * KST + ks * 32 + grp * 8];
#pragma unroll
            for (int mi = 0; mi < 2; mi++)
#pragma unroll
                for (int di = 0; di < 4; di++)
                    oacc[mi][di] = __builtin_amdgcn_mfma_f32_16x16x32_bf16(
                        vf[di], pf[mi], oacc[mi][di], 0, 0, 0);
        }
    }

    // epilogue: O^T/l -> out[b][s][h*64+d], float4 stores (d consecutive)
#pragma unroll
    for (int mi = 0; mi < 2; mi++) {
        const float inv = 1.0f / rsum[mi];
        const int s = m0 + mi * 16 + frow;
#pragma unroll
        for (int di = 0; di < 4; di++) {
            f32x4 o = oacc[mi][di] * inv;
            const int d0 = di * 16 + grp * 4;
            *(f32x4*)&out[(bb * 1024 + s) * 768 + h * 64 + d0] = o;
        }
    }
}

// ---------------------------------------------------------------- residual + LN (f32)
__global__ __launch_bounds__(256) void kln(
        const float* __restrict__ x,
        const float* __restrict__ gamma,
        const float* __restrict__ beta,
        float* __restrict__ out) {
    __shared__ float red[8];
    const int row = blockIdx.x;
    const int tid = threadIdx.x;
    const float* xr = x + row * 768;
    float* orow = out + row * 768;
    float y[3], sum = 0.f, sumsq = 0.f;
#pragma unroll
    for (int i = 0; i < 3; i++) {
        const int e = tid + i * 256;
        const float v = xr[e] + orow[e];
        y[i] = v; sum += v; sumsq += v * v;
    }
#pragma unroll
    for (int o = 1; o < 64; o <<= 1) {
        sum += __shfl_xor(sum, o, 64);
        sumsq += __shfl_xor(sumsq, o, 64);
    }
    const int w = tid >> 6, lane = tid & 63;
    if (lane == 0) { red[w] = sum; red[4 + w] = sumsq; }
    __syncthreads();
    sum = red[0] + red[1] + red[2] + red[3];
    sumsq = red[4] + red[5] + red[6] + red[7];
    const float mean = sum * (1.0f / 768.0f);
    const float var = sumsq * (1.0f / 768.0f) - mean * mean;
    const float rs = rsqrtf(var + 1e-5f);
#pragma unroll
    for (int i = 0; i < 3; i++) {
        const int e = tid + i * 256;
        orow[e] = (y[i] - mean) * rs * gamma[e] + beta[e];
    }
}

// ---------------------------------------------------------------- launch
extern "C" void kernel_launch(void* const* d_in, const int* in_sizes, int n_in,
                              void* d_out, int out_size, void* d_ws, size_t ws_size,
                              hipStream_t stream) {
    (void)in_sizes; (void)n_in; (void)out_size; (void)ws_size;
    const float* x     = (const float*)d_in[0];
    const float* wqkv  = (const float*)d_in[1];
    const float* bqkv  = (const float*)d_in[2];
    const float* gamma = (const float*)d_in[3];
    const float* beta  = (const float*)d_in[4];
    float* out = (float*)d_out;
    unsigned short* ws = (unsigned short*)d_ws;

    unsigned short* wt = ws;                       // 2304*768  bf16
    unsigned short* q  = wt + 2304 * 768;          // 96*1024*64 bf16
    unsigned short* k  = q + 96 * 1024 * 64;       // 96*1024*64 bf16
    unsigned short* vt = k + 96 * 1024 * 64;       // 96*64*1024 bf16

    ktrans<<<dim3(72, 24), dim3(32, 8), 0, stream>>>(wqkv, wt);
    kgemm<<<dim3(18, 64), 256, 0, stream>>>(x, wt, bqkv, q, k, vt);
    kattn<<<dim3(96, 8), 256, 0, stream>>>(q, k, vt, out);
    kln<<<8192, 256, 0, stream>>>(x, gamma, beta, out);
}